// Round 8
// baseline (42.799 us; speedup 1.0000x reference)
//
#include <hip/hip_runtime.h>

#define LENGTH 4000
#define NPAD   4096
#define NB     8
#define CH     64
#define NP     4

// 16-point unnormalized Sylvester FWHT, fully in registers (static indices).
__device__ __forceinline__ void fwht16(float v[16]) {
    #pragma unroll
    for (int h = 1; h < 16; h <<= 1)
        #pragma unroll
        for (int j = 0; j < 16; j += 2 * h)
            #pragma unroll
            for (int k = j; k < j + h; ++k) {
                float u = v[k], w = v[k + h];
                v[k] = u + w; v[k + h] = u - w;
            }
}

// ---------------- K1: forward FWHT (register radix-16^3) ----------------------
__global__ __launch_bounds__(256) void k_fwht_fwd(const float* __restrict__ x,
                                                  float* __restrict__ f1) {
    __shared__ float lds[256 * 17];        // padded stride 17: <=2-way bank alias
    const int row = blockIdx.x;            // b*64 + i
    const int t = threadIdx.x;
    const int A = t >> 4, B = t & 15;

    float v[16];
    if (t < 250) {                         // 250*16 == 4000: clean tail
        const float* xr = x + (size_t)row * LENGTH + t * 16;
        #pragma unroll
        for (int q = 0; q < 4; ++q) {
            float4 lv = *(const float4*)(xr + q * 4);
            v[q * 4 + 0] = lv.x; v[q * 4 + 1] = lv.y;
            v[q * 4 + 2] = lv.z; v[q * 4 + 3] = lv.w;
        }
    } else {
        #pragma unroll
        for (int c = 0; c < 16; ++c) v[c] = 0.f;
    }
    fwht16(v);                             // over C

    #pragma unroll
    for (int c = 0; c < 16; ++c)
        lds[(A * 16 + c) * 17 + B] = v[c];
    __syncthreads();
    {
        const int base = (A * 16 + B) * 17;
        #pragma unroll
        for (int b = 0; b < 16; ++b) v[b] = lds[base + b];
    }
    __syncthreads();
    fwht16(v);                             // over B

    const int C = t & 15;
    #pragma unroll
    for (int b = 0; b < 16; ++b)
        lds[(b * 16 + C) * 17 + A] = v[b];
    __syncthreads();
    {
        const int base2 = t * 17;
        #pragma unroll
        for (int a = 0; a < 16; ++a) v[a] = lds[base2 + a];
    }
    fwht16(v);                             // over A

    float* fr = f1 + (size_t)row * NPAD;
    #pragma unroll
    for (int a = 0; a < 16; ++a)
        fr[a * 256 + t] = v[a];
}

// ---------------- K2: SGPR-W channel mix --------------------------------------
// Wave owns 4 consecutive o's (wave-uniform -> W via scalar pipe), lane owns
// one n. p hoisted: c read ONCE per i (1 ds_read_b32), 16 FMAs against SGPR
// W operands. acc[4][4] fully static. DS ops/wave: 64 (was 512).
__global__ __launch_bounds__(256) void k_mix(const float* __restrict__ f1,
                                             const float* __restrict__ W,
                                             const float* __restrict__ T,
                                             const float* __restrict__ v,
                                             float* __restrict__ f6) {
    __shared__ float sC[CH][64];           // [i][n], 16 KB
    const int bid = blockIdx.x;            // b*256 + nch*4 + oq
    const int oq = bid & 3;
    const int nch = (bid >> 2) & 63;
    const int b = bid >> 8;
    const int nbase = nch * 64;
    const int t = threadIdx.x;
    const int lane = t & 63;
    const int wave = __builtin_amdgcn_readfirstlane(t >> 6);
    const int o0 = oq * 16 + wave * 4;     // wave-uniform

    // stage f1 tile: [64 i][64 n]
    #pragma unroll
    for (int r = 0; r < 4; ++r) {
        int q = r * 256 + t;
        int i = q >> 4, n4 = q & 15;
        *(float4*)(&sC[i][n4 * 4]) =
            *(const float4*)(f1 + (size_t)(b * CH + i) * NPAD + nbase + n4 * 4);
    }
    __syncthreads();

    const float* wbase = W + (size_t)o0 * CH;  // + p*CH*CH + j*CH + i (uniform)
    float acc[NP][4];
    #pragma unroll
    for (int p = 0; p < NP; ++p)
        #pragma unroll
        for (int j = 0; j < 4; ++j) acc[p][j] = 0.f;

    #pragma unroll 4
    for (int i = 0; i < CH; ++i) {
        float c = sC[i][lane];             // dense row read, 2-way free
        #pragma unroll
        for (int p = 0; p < NP; ++p)
            #pragma unroll
            for (int j = 0; j < 4; ++j)
                acc[p][j] = fmaf(wbase[p * CH * CH + j * CH + i], c, acc[p][j]);
    }

    float out[4] = {0.f, 0.f, 0.f, 0.f};
    #pragma unroll
    for (int p = 0; p < NP; ++p) {
        float vp = v[(size_t)p * NPAD + nbase + lane];
        float tp = fabsf(T[(size_t)p * NPAD + nbase + lane]);
        #pragma unroll
        for (int j = 0; j < 4; ++j) {
            float c = vp * acc[p][j];
            float a = fabsf(c) - tp;
            out[j] += (a > 0.f) ? copysignf(a, c) : 0.f;
        }
    }
    #pragma unroll
    for (int j = 0; j < 4; ++j)
        f6[(size_t)(b * CH + o0 + j) * NPAD + nbase + lane] = out[j];
}

// ---------------- K3: inverse FWHT (register radix), scale, trunc, +x --------
__global__ __launch_bounds__(256) void k_fwht_inv(const float* __restrict__ f6,
                                                  const float* __restrict__ x,
                                                  float* __restrict__ out) {
    __shared__ float lds[256 * 17];
    const int row = blockIdx.x;            // b*64 + o
    const int t = threadIdx.x;
    const int A = t >> 4, B = t & 15;

    float v[16];
    {
        const float* fr = f6 + (size_t)row * NPAD + t * 16;
        #pragma unroll
        for (int q = 0; q < 4; ++q) {
            float4 lv = *(const float4*)(fr + q * 4);
            v[q * 4 + 0] = lv.x; v[q * 4 + 1] = lv.y;
            v[q * 4 + 2] = lv.z; v[q * 4 + 3] = lv.w;
        }
    }
    fwht16(v);

    #pragma unroll
    for (int c = 0; c < 16; ++c)
        lds[(A * 16 + c) * 17 + B] = v[c];
    __syncthreads();
    {
        const int base = (A * 16 + B) * 17;
        #pragma unroll
        for (int b = 0; b < 16; ++b) v[b] = lds[base + b];
    }
    __syncthreads();
    fwht16(v);

    const int C = t & 15;
    #pragma unroll
    for (int b = 0; b < 16; ++b)
        lds[(b * 16 + C) * 17 + A] = v[b];
    __syncthreads();
    {
        const int base2 = t * 17;
        #pragma unroll
        for (int a = 0; a < 16; ++a) v[a] = lds[base2 + a];
    }
    fwht16(v);

    const float scale = 1.f / NPAD;
    const float* xr = x + (size_t)row * LENGTH;
    float* orow = out + (size_t)row * LENGTH;
    #pragma unroll
    for (int a = 0; a < 16; ++a) {
        int n = a * 256 + t;
        if (n < LENGTH) orow[n] = v[a] * scale + xr[n];
    }
}

extern "C" void kernel_launch(void* const* d_in, const int* in_sizes, int n_in,
                              void* d_out, int out_size, void* d_ws, size_t ws_size,
                              hipStream_t stream) {
    (void)in_sizes; (void)n_in; (void)out_size; (void)ws_size;
    const float* x = (const float*)d_in[0];
    const float* W = (const float*)d_in[1];
    const float* T = (const float*)d_in[2];
    const float* v = (const float*)d_in[3];
    float* out = (float*)d_out;
    float* f1 = (float*)d_ws;
    float* f6 = f1 + (size_t)NB * CH * NPAD;

    k_fwht_fwd<<<NB * CH, 256, 0, stream>>>(x, f1);
    k_mix<<<NB * 64 * 4, 256, 0, stream>>>(f1, W, T, v, f6);
    k_fwht_inv<<<NB * CH, 256, 0, stream>>>(f6, x, out);
}

// Round 9
// 23.561 us; speedup vs baseline: 1.8165x; 1.8165x over previous
//
#include <hip/hip_runtime.h>
#include <hip/hip_bf16.h>

#define LENGTH 4000
#define NPAD   4096
#define NB     8
#define CH     64
#define NP     4
#define NT2    32               // n-cols per k_mix block
#define BSTR   72               // sBt row stride (ushorts) = 9*16B: aligned b128 rows

using ushort8 = __attribute__((ext_vector_type(8))) unsigned short;
using short8v = __attribute__((ext_vector_type(8))) short;
using f32x4   = __attribute__((ext_vector_type(4))) float;

__device__ __forceinline__ unsigned short f2bu(float f) {
    __hip_bfloat16 h = __float2bfloat16(f);
    return __builtin_bit_cast(unsigned short, h);
}
__device__ __forceinline__ float bu2f(unsigned short u) {
    __hip_bfloat16 h = __builtin_bit_cast(__hip_bfloat16, u);
    return __bfloat162float(h);
}

// 16-point unnormalized Sylvester FWHT, fully in registers (static indices).
__device__ __forceinline__ void fwht16(float v[16]) {
    #pragma unroll
    for (int h = 1; h < 16; h <<= 1)
        #pragma unroll
        for (int j = 0; j < 16; j += 2 * h)
            #pragma unroll
            for (int k = j; k < j + h; ++k) {
                float u = v[k], w = v[k + h];
                v[k] = u + w; v[k + h] = u - w;
            }
}

// ---------------- K1: forward FWHT (register radix-16^3) -> f1 bf16 -----------
// Also converts W -> bf16 once (blocks 0..255, one W row each).
__global__ __launch_bounds__(256) void k_fwht_fwd(const float* __restrict__ x,
                                                  unsigned short* __restrict__ f1b,
                                                  const float* __restrict__ W,
                                                  unsigned short* __restrict__ Wb) {
    __shared__ float lds[256 * 17];
    const int row = blockIdx.x;            // b*64 + i
    const int t = threadIdx.x;
    const int A = t >> 4, B = t & 15;

    if (row < NP * CH && t < CH)           // W[po][i] -> bf16 copy
        Wb[row * CH + t] = f2bu(W[row * CH + t]);

    float v[16];
    if (t < 250) {                         // 250*16 == 4000
        const float* xr = x + (size_t)row * LENGTH + t * 16;
        #pragma unroll
        for (int q = 0; q < 4; ++q) {
            float4 lv = *(const float4*)(xr + q * 4);
            v[q * 4 + 0] = lv.x; v[q * 4 + 1] = lv.y;
            v[q * 4 + 2] = lv.z; v[q * 4 + 3] = lv.w;
        }
    } else {
        #pragma unroll
        for (int c = 0; c < 16; ++c) v[c] = 0.f;
    }
    fwht16(v);                             // over C

    #pragma unroll
    for (int c = 0; c < 16; ++c)
        lds[(A * 16 + c) * 17 + B] = v[c];
    __syncthreads();
    {
        const int base = (A * 16 + B) * 17;
        #pragma unroll
        for (int b = 0; b < 16; ++b) v[b] = lds[base + b];
    }
    __syncthreads();
    fwht16(v);                             // over B

    const int C = t & 15;
    #pragma unroll
    for (int b = 0; b < 16; ++b)
        lds[(b * 16 + C) * 17 + A] = v[b];
    __syncthreads();
    {
        const int base2 = t * 17;
        #pragma unroll
        for (int a = 0; a < 16; ++a) v[a] = lds[base2 + a];
    }
    fwht16(v);                             // over A

    unsigned short* fr = f1b + (size_t)row * NPAD;
    #pragma unroll
    for (int a = 0; a < 16; ++a)
        fr[a * 256 + t] = f2bu(v[a]);      // 512B contiguous per instr
}

// ---------------- K2: MFMA channel mix ---------------------------------------
// C[po][n] = Wb[po][i] * f1[b][i][n], 16x16x32 bf16 MFMA, fp32 accum.
// Block: one b, 32 n-cols, all 256 po. Wave w: o-range [w*16,w*16+16), all p.
__global__ __launch_bounds__(256) void k_mix(const unsigned short* __restrict__ f1b,
                                             const unsigned short* __restrict__ Wb,
                                             const float* __restrict__ T,
                                             const float* __restrict__ v,
                                             unsigned short* __restrict__ f6b) {
    __shared__ unsigned short sBt[NT2 * BSTR];   // [n][i] transposed, 4.6 KB
    const int bid = blockIdx.x;            // b*128 + nchunk
    const int nchunk = bid & 127;
    const int b = bid >> 7;
    const int nbase = nchunk * NT2;
    const int t = threadIdx.x;
    const int lane = t & 63;
    const int w = t >> 6;                  // wave id 0..3
    const int l15 = lane & 15, lq = lane >> 4;

    // stage f1 tile 64i x 32n -> sBt[n][i]; thread: i=t>>2, 8 n's
    {
        const int i = t >> 2, n0 = (t & 3) * 8;
        const unsigned short* src =
            f1b + (size_t)(b * CH + i) * NPAD + nbase + n0;
        ushort8 r = *(const ushort8*)src;
        #pragma unroll
        for (int j = 0; j < 8; ++j)
            sBt[(n0 + j) * BSTR + i] = r[j];
    }

    // A fragments from global (L2-hot 32KB): Mtile = p*4+w -> po base p*64+w*16
    short8v afrag[NP][2];
    #pragma unroll
    for (int p = 0; p < NP; ++p)
        #pragma unroll
        for (int ks = 0; ks < 2; ++ks)
            afrag[p][ks] = *(const short8v*)(Wb +
                (size_t)(p * 64 + w * 16 + l15) * CH + ks * 32 + lq * 8);

    __syncthreads();

    short8v bfrag[2][2];                   // [nt][ks]
    #pragma unroll
    for (int nt = 0; nt < 2; ++nt)
        #pragma unroll
        for (int ks = 0; ks < 2; ++ks)
            bfrag[nt][ks] = *(const short8v*)(
                &sBt[(nt * 16 + l15) * BSTR + ks * 32 + lq * 8]);

    f32x4 acc[NP][2];
    #pragma unroll
    for (int p = 0; p < NP; ++p)
        #pragma unroll
        for (int nt = 0; nt < 2; ++nt) {
            acc[p][nt] = (f32x4){0.f, 0.f, 0.f, 0.f};
            #pragma unroll
            for (int ks = 0; ks < 2; ++ks)
                acc[p][nt] = __builtin_amdgcn_mfma_f32_16x16x32_bf16(
                    afrag[p][ks], bfrag[nt][ks], acc[p][nt], 0, 0, 0);
        }

    // epilogue: v*, soft-threshold, sum over p; C layout col=lane&15,
    // row=(lane>>4)*4+reg  [learn_hip m89]
    #pragma unroll
    for (int nt = 0; nt < 2; ++nt) {
        const int n = nbase + nt * 16 + l15;
        float outv[4] = {0.f, 0.f, 0.f, 0.f};
        #pragma unroll
        for (int p = 0; p < NP; ++p) {
            const float vp = v[(size_t)p * NPAD + n];
            const float tp = fabsf(T[(size_t)p * NPAD + n]);
            #pragma unroll
            for (int r = 0; r < 4; ++r) {
                float c = vp * acc[p][nt][r];
                float a = fabsf(c) - tp;
                outv[r] += (a > 0.f) ? copysignf(a, c) : 0.f;
            }
        }
        #pragma unroll
        for (int r = 0; r < 4; ++r) {
            const int o = w * 16 + lq * 4 + r;
            f6b[(size_t)(b * CH + o) * NPAD + n] = f2bu(outv[r]);
        }
    }
}

// ---------------- K3: inverse FWHT (register radix), scale, trunc, +x --------
__global__ __launch_bounds__(256) void k_fwht_inv(const unsigned short* __restrict__ f6b,
                                                  const float* __restrict__ x,
                                                  float* __restrict__ out) {
    __shared__ float lds[256 * 17];
    const int row = blockIdx.x;            // b*64 + o
    const int t = threadIdx.x;
    const int A = t >> 4, B = t & 15;

    float v[16];
    {
        const unsigned short* fr = f6b + (size_t)row * NPAD + t * 16;
        ushort8 r0 = *(const ushort8*)(fr);
        ushort8 r1 = *(const ushort8*)(fr + 8);
        #pragma unroll
        for (int j = 0; j < 8; ++j) { v[j] = bu2f(r0[j]); v[8 + j] = bu2f(r1[j]); }
    }
    fwht16(v);

    #pragma unroll
    for (int c = 0; c < 16; ++c)
        lds[(A * 16 + c) * 17 + B] = v[c];
    __syncthreads();
    {
        const int base = (A * 16 + B) * 17;
        #pragma unroll
        for (int b = 0; b < 16; ++b) v[b] = lds[base + b];
    }
    __syncthreads();
    fwht16(v);

    const int C = t & 15;
    #pragma unroll
    for (int b = 0; b < 16; ++b)
        lds[(b * 16 + C) * 17 + A] = v[b];
    __syncthreads();
    {
        const int base2 = t * 17;
        #pragma unroll
        for (int a = 0; a < 16; ++a) v[a] = lds[base2 + a];
    }
    fwht16(v);

    const float scale = 1.f / NPAD;
    const float* xr = x + (size_t)row * LENGTH;
    float* orow = out + (size_t)row * LENGTH;
    #pragma unroll
    for (int a = 0; a < 16; ++a) {
        int n = a * 256 + t;
        if (n < LENGTH) orow[n] = v[a] * scale + xr[n];
    }
}

extern "C" void kernel_launch(void* const* d_in, const int* in_sizes, int n_in,
                              void* d_out, int out_size, void* d_ws, size_t ws_size,
                              hipStream_t stream) {
    (void)in_sizes; (void)n_in; (void)out_size; (void)ws_size;
    const float* x = (const float*)d_in[0];
    const float* W = (const float*)d_in[1];
    const float* T = (const float*)d_in[2];
    const float* v = (const float*)d_in[3];
    float* out = (float*)d_out;
    unsigned short* f1b = (unsigned short*)d_ws;                 // 4 MB
    unsigned short* f6b = f1b + (size_t)NB * CH * NPAD;          // 4 MB
    unsigned short* Wb  = f6b + (size_t)NB * CH * NPAD;          // 32 KB

    k_fwht_fwd<<<NB * CH, 256, 0, stream>>>(x, f1b, W, Wb);
    k_mix<<<NB * (NPAD / NT2), 256, 0, stream>>>(f1b, Wb, T, v, f6b);
    k_fwht_inv<<<NB * CH, 256, 0, stream>>>(f6b, x, out);
}

// Round 10
// 23.168 us; speedup vs baseline: 1.8473x; 1.0170x over previous
//
#include <hip/hip_runtime.h>
#include <hip/hip_bf16.h>

#define LENGTH 4000
#define NPAD   4096
#define NB     8
#define CH     64
#define NP     4
#define NT2    32               // n-cols per k_mix block
#define BSTR   72               // sBt row stride (ushorts) = 9*16B: aligned b128 rows

using ushort8 = __attribute__((ext_vector_type(8))) unsigned short;
using short8v = __attribute__((ext_vector_type(8))) short;
using f32x4   = __attribute__((ext_vector_type(4))) float;

__device__ __forceinline__ unsigned short f2bu(float f) {
    __hip_bfloat16 h = __float2bfloat16(f);
    return __builtin_bit_cast(unsigned short, h);
}
__device__ __forceinline__ float bu2f(unsigned short u) {
    __hip_bfloat16 h = __builtin_bit_cast(__hip_bfloat16, u);
    return __bfloat162float(h);
}

// 8-point unnormalized Sylvester FWHT in registers.
__device__ __forceinline__ void fwht8(float v[8]) {
    #pragma unroll
    for (int h = 1; h < 8; h <<= 1)
        #pragma unroll
        for (int j = 0; j < 8; j += 2 * h)
            #pragma unroll
            for (int k = j; k < j + h; ++k) {
                float a = v[k], b = v[k + h];
                v[k] = a + b; v[k + h] = a - b;
            }
}

// Padded LDS address: every 8-float group padded by 1 -> all digit-stride
// exchanges are <=3-way bank aliased.
#define LADR(n) ((((n) >> 3) * 9) + ((n) & 7))
#define LDSZ 4608   // 4096/8*9

// ---------------- K1: forward FWHT (radix 8^4, 512 thr) -> f1 bf16 ------------
// n = d3*512 + d2*64 + d1*8 + d0. Thread t starts owning d0 (8 contiguous).
// 4 register H8 stages, 3 LDS transposes (A/B double buffer, 3 barriers).
__global__ __launch_bounds__(512) void k_fwht_fwd(const float* __restrict__ x,
                                                  unsigned short* __restrict__ f1b,
                                                  const float* __restrict__ W,
                                                  unsigned short* __restrict__ Wb) {
    __shared__ float ldsA[LDSZ];
    __shared__ float ldsB[LDSZ];
    const int row = blockIdx.x;            // b*64 + i
    const int t = threadIdx.x;

    if (row < NP * CH && t < CH)           // W[po][i] -> bf16 copy (once)
        Wb[row * CH + t] = f2bu(W[row * CH + t]);

    float v[8];
    if (t < 500) {                         // 500*8 == 4000
        const float* xr = x + (size_t)row * LENGTH + t * 8;
        float4 a = *(const float4*)xr, b = *(const float4*)(xr + 4);
        v[0]=a.x; v[1]=a.y; v[2]=a.z; v[3]=a.w;
        v[4]=b.x; v[5]=b.y; v[6]=b.z; v[7]=b.w;
    } else {
        #pragma unroll
        for (int j = 0; j < 8; ++j) v[j] = 0.f;
    }
    fwht8(v);                              // over d0

    // T1: own d1.  sigma1(t,j) = (t>>3)*64 + j*8 + (t&7)
    #pragma unroll
    for (int j = 0; j < 8; ++j) ldsA[LADR(t * 8 + j)] = v[j];
    __syncthreads();
    const int s1 = (t >> 3) * 64 + (t & 7);
    #pragma unroll
    for (int j = 0; j < 8; ++j) v[j] = ldsA[LADR(s1 + j * 8)];
    fwht8(v);                              // over d1

    // T2: own d2.  sigma2(t,j) = (t>>6)*512 + j*64 + ((t>>3)&7)*8 + (t&7)
    #pragma unroll
    for (int j = 0; j < 8; ++j) ldsB[LADR(s1 + j * 8)] = v[j];
    __syncthreads();
    const int s2 = (t >> 6) * 512 + ((t >> 3) & 7) * 8 + (t & 7);
    #pragma unroll
    for (int j = 0; j < 8; ++j) v[j] = ldsB[LADR(s2 + j * 64)];
    fwht8(v);                              // over d2

    // T3: own d3.  sigma3(t,j) = j*512 + t   (bar2 already fenced T1 reads of A)
    #pragma unroll
    for (int j = 0; j < 8; ++j) ldsA[LADR(s2 + j * 64)] = v[j];
    __syncthreads();
    #pragma unroll
    for (int j = 0; j < 8; ++j) v[j] = ldsA[LADR(j * 512 + t)];
    fwht8(v);                              // over d3

    unsigned short* fr = f1b + (size_t)row * NPAD;
    #pragma unroll
    for (int j = 0; j < 8; ++j)            // 128B contiguous per wave-instr
        fr[j * 512 + t] = f2bu(v[j]);
}

// ---------------- K2: MFMA channel mix (unchanged from R9) --------------------
__global__ __launch_bounds__(256) void k_mix(const unsigned short* __restrict__ f1b,
                                             const unsigned short* __restrict__ Wb,
                                             const float* __restrict__ T,
                                             const float* __restrict__ v,
                                             unsigned short* __restrict__ f6b) {
    __shared__ unsigned short sBt[NT2 * BSTR];   // [n][i] transposed, 4.6 KB
    const int bid = blockIdx.x;            // b*128 + nchunk
    const int nchunk = bid & 127;
    const int b = bid >> 7;
    const int nbase = nchunk * NT2;
    const int t = threadIdx.x;
    const int lane = t & 63;
    const int w = t >> 6;                  // wave id 0..3
    const int l15 = lane & 15, lq = lane >> 4;

    {
        const int i = t >> 2, n0 = (t & 3) * 8;
        const unsigned short* src =
            f1b + (size_t)(b * CH + i) * NPAD + nbase + n0;
        ushort8 r = *(const ushort8*)src;
        #pragma unroll
        for (int j = 0; j < 8; ++j)
            sBt[(n0 + j) * BSTR + i] = r[j];
    }

    short8v afrag[NP][2];
    #pragma unroll
    for (int p = 0; p < NP; ++p)
        #pragma unroll
        for (int ks = 0; ks < 2; ++ks)
            afrag[p][ks] = *(const short8v*)(Wb +
                (size_t)(p * 64 + w * 16 + l15) * CH + ks * 32 + lq * 8);

    __syncthreads();

    short8v bfrag[2][2];
    #pragma unroll
    for (int nt = 0; nt < 2; ++nt)
        #pragma unroll
        for (int ks = 0; ks < 2; ++ks)
            bfrag[nt][ks] = *(const short8v*)(
                &sBt[(nt * 16 + l15) * BSTR + ks * 32 + lq * 8]);

    f32x4 acc[NP][2];
    #pragma unroll
    for (int p = 0; p < NP; ++p)
        #pragma unroll
        for (int nt = 0; nt < 2; ++nt) {
            acc[p][nt] = (f32x4){0.f, 0.f, 0.f, 0.f};
            #pragma unroll
            for (int ks = 0; ks < 2; ++ks)
                acc[p][nt] = __builtin_amdgcn_mfma_f32_16x16x32_bf16(
                    afrag[p][ks], bfrag[nt][ks], acc[p][nt], 0, 0, 0);
        }

    #pragma unroll
    for (int nt = 0; nt < 2; ++nt) {
        const int n = nbase + nt * 16 + l15;
        float outv[4] = {0.f, 0.f, 0.f, 0.f};
        #pragma unroll
        for (int p = 0; p < NP; ++p) {
            const float vp = v[(size_t)p * NPAD + n];
            const float tp = fabsf(T[(size_t)p * NPAD + n]);
            #pragma unroll
            for (int r = 0; r < 4; ++r) {
                float c = vp * acc[p][nt][r];
                float a = fabsf(c) - tp;
                outv[r] += (a > 0.f) ? copysignf(a, c) : 0.f;
            }
        }
        #pragma unroll
        for (int r = 0; r < 4; ++r) {
            const int o = w * 16 + lq * 4 + r;
            f6b[(size_t)(b * CH + o) * NPAD + n] = f2bu(outv[r]);
        }
    }
}

// ---------------- K3: inverse FWHT (radix 8^4), scale, trunc, +x --------------
__global__ __launch_bounds__(512) void k_fwht_inv(const unsigned short* __restrict__ f6b,
                                                  const float* __restrict__ x,
                                                  float* __restrict__ out) {
    __shared__ float ldsA[LDSZ];
    __shared__ float ldsB[LDSZ];
    const int row = blockIdx.x;            // b*64 + o
    const int t = threadIdx.x;

    float v[8];
    {
        const unsigned short* fr = f6b + (size_t)row * NPAD + t * 8;
        ushort8 r = *(const ushort8*)fr;   // 1KB contiguous per wave-instr
        #pragma unroll
        for (int j = 0; j < 8; ++j) v[j] = bu2f(r[j]);
    }
    fwht8(v);                              // d0

    #pragma unroll
    for (int j = 0; j < 8; ++j) ldsA[LADR(t * 8 + j)] = v[j];
    __syncthreads();
    const int s1 = (t >> 3) * 64 + (t & 7);
    #pragma unroll
    for (int j = 0; j < 8; ++j) v[j] = ldsA[LADR(s1 + j * 8)];
    fwht8(v);                              // d1

    #pragma unroll
    for (int j = 0; j < 8; ++j) ldsB[LADR(s1 + j * 8)] = v[j];
    __syncthreads();
    const int s2 = (t >> 6) * 512 + ((t >> 3) & 7) * 8 + (t & 7);
    #pragma unroll
    for (int j = 0; j < 8; ++j) v[j] = ldsB[LADR(s2 + j * 64)];
    fwht8(v);                              // d2

    #pragma unroll
    for (int j = 0; j < 8; ++j) ldsA[LADR(s2 + j * 64)] = v[j];
    __syncthreads();
    #pragma unroll
    for (int j = 0; j < 8; ++j) v[j] = ldsA[LADR(j * 512 + t)];
    fwht8(v);                              // d3

    const float scale = 1.f / NPAD;
    const float* xr = x + (size_t)row * LENGTH;
    float* orow = out + (size_t)row * LENGTH;
    #pragma unroll
    for (int j = 0; j < 8; ++j) {
        const int n = j * 512 + t;
        if (n < LENGTH) orow[n] = v[j] * scale + xr[n];
    }
}

extern "C" void kernel_launch(void* const* d_in, const int* in_sizes, int n_in,
                              void* d_out, int out_size, void* d_ws, size_t ws_size,
                              hipStream_t stream) {
    (void)in_sizes; (void)n_in; (void)out_size; (void)ws_size;
    const float* x = (const float*)d_in[0];
    const float* W = (const float*)d_in[1];
    const float* T = (const float*)d_in[2];
    const float* v = (const float*)d_in[3];
    float* out = (float*)d_out;
    unsigned short* f1b = (unsigned short*)d_ws;                 // 4 MB
    unsigned short* f6b = f1b + (size_t)NB * CH * NPAD;          // 4 MB
    unsigned short* Wb  = f6b + (size_t)NB * CH * NPAD;          // 32 KB

    k_fwht_fwd<<<NB * CH, 512, 0, stream>>>(x, f1b, W, Wb);
    k_mix<<<NB * (NPAD / NT2), 256, 0, stream>>>(f1b, Wb, T, v, f6b);
    k_fwht_inv<<<NB * CH, 512, 0, stream>>>(f6b, x, out);
}